// Round 19
// baseline (73.975 us; speedup 1.0000x reference)
//
#include <hip/hip_runtime.h>
#include <hip/hip_bf16.h>

constexpr int B = 8, N = 2048, FIN = 128, FOUT = 64;

typedef __attribute__((ext_vector_type(8))) short short8;
typedef __attribute__((ext_vector_type(4))) float f32x4;

// f32 pair -> packed bf16 (RNE) via v_cvt_pk_bf16_f32
__device__ __forceinline__ unsigned int pk_bf16(float lo, float hi) {
    union { __hip_bfloat162 h2; unsigned int u; } c;
    c.h2 = __float22bfloat162_rn(float2{lo, hi});
    return c.u;
}
__device__ __forceinline__ unsigned short f2bf(float f) {
    return (unsigned short)(pk_bf16(f, 0.f) & 0xFFFFu);
}

// ---- kA: [blocks 0..127] h = inp@W via bf16 MFMA -> hP; s1/s2 in f32
//      [blocks 128..383] adj -> 1-bit mask   (unchanged from R18)
__global__ __launch_bounds__(512, 2) void kA(
        const float* __restrict__ inp, const float* __restrict__ W,
        const float* __restrict__ a, const int* __restrict__ adj,
        unsigned short* __restrict__ hP, float* __restrict__ s1,
        float* __restrict__ s2, unsigned long long* __restrict__ adjbits) {
    __shared__ float wa1l[128], wa2l[128];
    __shared__ unsigned short wT[64][136];
    __shared__ unsigned short aT[128][136];

    int bx = blockIdx.x, t = threadIdx.x, w = t >> 6, lane = t & 63;

    if (bx >= 128) {                              // ---- adj bit-pack ----
        int row = (bx - 128) * 8 + w;
        const int* ar = adj + (size_t)row * N;
        unsigned long long* br = adjbits + (size_t)row * 32;
        #pragma unroll 8
        for (int wq = 0; wq < 32; ++wq) {
            unsigned long long m = __ballot(ar[wq * 64 + lane] > 0);
            if (lane == 0) br[wq] = m;
        }
        return;
    }

    int b = bx >> 4, i0 = (bx & 15) * 128;

    if (t < 128) {
        const float* wr = W + t * FOUT;
        float acc1 = 0.f;
        #pragma unroll 16
        for (int o = 0; o < 64; ++o) acc1 = fmaf(wr[o], a[o], acc1);
        wa1l[t] = acc1;
    } else if (t < 256) {
        int k = t - 128;
        const float* wr = W + k * FOUT;
        float acc2 = 0.f;
        #pragma unroll 16
        for (int o = 0; o < 64; ++o) acc2 = fmaf(wr[o], a[64 + o], acc2);
        wa2l[k] = acc2;
    } else {
        int t2 = t - 256;
        int o = t2 & 63, kg = t2 >> 6;
        #pragma unroll 8
        for (int kk = 0; kk < 32; ++kk) {
            int k = kg * 32 + kk;
            wT[o][k] = f2bf(W[k * FOUT + o]);
        }
    }
    __syncthreads();

    {
        int row = t >> 2, seg = t & 3;
        const float* ip = inp + ((size_t)b * N + i0 + row) * FIN + seg * 32;
        float s1p = 0.f, s2p = 0.f;
        #pragma unroll
        for (int q = 0; q < 8; ++q) {
            float4 v = *(const float4*)&ip[q * 4];
            int k = seg * 32 + q * 4;
            s1p += v.x * wa1l[k] + v.y * wa1l[k + 1] + v.z * wa1l[k + 2] + v.w * wa1l[k + 3];
            s2p += v.x * wa2l[k] + v.y * wa2l[k + 1] + v.z * wa2l[k + 2] + v.w * wa2l[k + 3];
            unsigned int* dst = (unsigned int*)&aT[row][k];
            dst[0] = pk_bf16(v.x, v.y);
            dst[1] = pk_bf16(v.z, v.w);
        }
        s1p += __shfl_xor(s1p, 1); s1p += __shfl_xor(s1p, 2);
        s2p += __shfl_xor(s2p, 1); s2p += __shfl_xor(s2p, 2);
        if (seg == 0) {
            s1[(size_t)b * N + i0 + row] = s1p;
            s2[(size_t)b * N + i0 + row] = s2p;
        }
    }
    __syncthreads();

    int r = lane & 15, g = lane >> 4;
    int mloc = w * 16;
    f32x4 acc[4];
    #pragma unroll
    for (int nf = 0; nf < 4; ++nf)
        #pragma unroll
        for (int q = 0; q < 4; ++q) acc[nf][q] = 0.f;
    #pragma unroll
    for (int ks = 0; ks < 4; ++ks) {
        short8 Af = *(const short8*)&aT[mloc + r][ks * 32 + g * 8];
        #pragma unroll
        for (int nf = 0; nf < 4; ++nf) {
            short8 Bf = *(const short8*)&wT[nf * 16 + r][ks * 32 + g * 8];
            acc[nf] = __builtin_amdgcn_mfma_f32_16x16x32_bf16(Af, Bf, acc[nf], 0, 0, 0);
        }
    }
    __syncthreads();

    #pragma unroll
    for (int nf = 0; nf < 4; ++nf)
        #pragma unroll
        for (int q = 0; q < 4; ++q)
            aT[mloc + g * 4 + q][nf * 16 + r] = f2bf(acc[nf][q]);
    __syncthreads();

    #pragma unroll
    for (int half = 0; half < 2; ++half) {
        int idx = t + half * 512;
        int kb_l = idx >> 8, nf = (idx >> 6) & 3, ln = idx & 63;
        int g2 = ln >> 4, r2 = ln & 15;
        union { short8 s8; unsigned short u[8]; } tw;
        #pragma unroll
        for (int e = 0; e < 8; ++e)
            tw.u[e] = aT[kb_l * 32 + g2 * 8 + e][nf * 16 + r2];
        int kbg = (bx & 15) * 4 + kb_l;
        *(short8*)&hP[((((size_t)b * 64 + kbg) * 4 + nf) << 9) + ln * 8] = tw.s8;
    }
}

// ---- K2 merged: heterogeneous 1 PV : 4 att interleave ---------------------
// bx%5==4 -> PV block (R18's proven rolled-window body; no rvg needed).
// else    -> att block: 4 waves = 4 batches of row i; wave self-computes its
//            row expsum then streams att = e~/sum. No inter-path dependency;
//            store-bound att waves co-schedule with MFMA/VALU PV waves (m114).
// __launch_bounds__(256,2): 256-VGPR budget; PV body's rolled outer loop
// bounds in-flight loads (R17/R18 lesson) -> no spills in either path.
__global__ __launch_bounds__(256, 2) void k2(
        const float* __restrict__ s1g, const float* __restrict__ s2g,
        const unsigned long long* __restrict__ adjbits,
        const unsigned short* __restrict__ hP,
        float* __restrict__ att, float* __restrict__ out) {
    __shared__ float s2l[N];                 // 8 KB (PV path only)
    __shared__ float s1l[16];
    __shared__ float ps[4][16];
    __shared__ float rvl[16];
    __shared__ float red[3][16][68];         // 13 KB

    int bx = blockIdx.x;
    int t = threadIdx.x, w = t >> 6, lane = t & 63;

    if (bx % 5 != 4) {
        // ================= att block =================
        int ai = (bx / 5) * 4 + (bx % 5);         // 0..4095
        int i = ai >> 1;                          // node row
        int b = (ai & 1) * 4 + w;                 // wave -> batch
        const unsigned long long* brow = adjbits + (size_t)i * 32;
        float s1v = s1g[(size_t)b * N + i];
        const float* s2b = s2g + (size_t)b * N;
        float* orow = att + ((size_t)b * N + i) * N;
        float rsum = 0.f;
        #pragma unroll
        for (int it = 0; it < 8; ++it) {
            int j = it * 256 + lane * 4;
            unsigned int bits = (unsigned int)(brow[j >> 6] >> (j & 63)) & 0xFu;
            float4 sv = *(const float4*)&s2b[j];
            float x0 = s1v + sv.x; x0 = fmaxf(x0, 0.2f * x0);
            float x1 = s1v + sv.y; x1 = fmaxf(x1, 0.2f * x1);
            float x2 = s1v + sv.z; x2 = fmaxf(x2, 0.2f * x2);
            float x3 = s1v + sv.w; x3 = fmaxf(x3, 0.2f * x3);
            rsum += (bits & 1u) ? __expf(x0) : 0.f;
            rsum += (bits & 2u) ? __expf(x1) : 0.f;
            rsum += (bits & 4u) ? __expf(x2) : 0.f;
            rsum += (bits & 8u) ? __expf(x3) : 0.f;
        }
        #pragma unroll
        for (int off = 1; off < 64; off <<= 1) rsum += __shfl_xor(rsum, off);
        float rv = 1.0f / rsum;
        #pragma unroll
        for (int it = 0; it < 8; ++it) {
            int j = it * 256 + lane * 4;
            unsigned int bits = (unsigned int)(brow[j >> 6] >> (j & 63)) & 0xFu;
            float4 sv = *(const float4*)&s2b[j];
            float x0 = s1v + sv.x; x0 = fmaxf(x0, 0.2f * x0);
            float x1 = s1v + sv.y; x1 = fmaxf(x1, 0.2f * x1);
            float x2 = s1v + sv.z; x2 = fmaxf(x2, 0.2f * x2);
            float x3 = s1v + sv.w; x3 = fmaxf(x3, 0.2f * x3);
            float4 o;
            o.x = (bits & 1u) ? __expf(x0) * rv : 0.f;
            o.y = (bits & 2u) ? __expf(x1) * rv : 0.f;
            o.z = (bits & 4u) ? __expf(x2) * rv : 0.f;
            o.w = (bits & 8u) ? __expf(x3) * rv : 0.f;
            *(float4*)&orow[j] = o;               // 1KB/wave contiguous
        }
        return;
    }

    // ================= PV block (R18 body) =================
    int L = bx / 5;                               // 0..1023
    int b = L & 7, m0 = (L >> 3) * 16;
    int kc = w;
    int r = lane & 15, g = lane >> 4;

    {
        int j = t * 8;
        *(float4*)&s2l[j]     = *(const float4*)&s2g[(size_t)b * N + j];
        *(float4*)&s2l[j + 4] = *(const float4*)&s2g[(size_t)b * N + j + 4];
    }
    if (t < 16) s1l[t] = s1g[(size_t)b * N + m0 + t];
    __syncthreads();

    float s1v = s1l[r];
    const unsigned long long* brow = adjbits + (size_t)(m0 + r) * 32 + kc * 8;
    const unsigned short* hpb = hP + (size_t)b * 64 * 4 * 512;

    f32x4 acc[4];
    #pragma unroll
    for (int nf = 0; nf < 4; ++nf)
        #pragma unroll
        for (int q = 0; q < 4; ++q) acc[nf][q] = 0.f;
    float rsum = 0.f;

    #pragma unroll 1
    for (int so = 0; so < 4; ++so) {             // rolled: bounds load window
        unsigned long long bw0 = brow[so * 2];
        unsigned long long bw1 = brow[so * 2 + 1];
        #pragma unroll
        for (int si = 0; si < 4; ++si) {         // full unroll: 4-step window
            int st = so * 4 + si;
            int jb = kc * 512 + st * 32 + g * 8;
            unsigned long long bwv = (si < 2) ? bw0 : bw1;
            unsigned int bits = (unsigned int)(bwv >> ((si & 1) * 32 + g * 8)) & 0xFFu;
            float4 sA = *(const float4*)&s2l[jb];
            float4 sB = *(const float4*)&s2l[jb + 4];
            union { short8 s8; unsigned int d[4]; } pk;
            {   // pairwise: <=4 live f32 temporaries at a time
                float xa, xb, pa, pb;
                xa = s1v + sA.x; xa = fmaxf(xa, 0.2f * xa);
                xb = s1v + sA.y; xb = fmaxf(xb, 0.2f * xb);
                pa = (bits & 1u) ? __expf(xa) : 0.f;
                pb = (bits & 2u) ? __expf(xb) : 0.f;
                rsum += pa + pb; pk.d[0] = pk_bf16(pa, pb);
                xa = s1v + sA.z; xa = fmaxf(xa, 0.2f * xa);
                xb = s1v + sA.w; xb = fmaxf(xb, 0.2f * xb);
                pa = (bits & 4u) ? __expf(xa) : 0.f;
                pb = (bits & 8u) ? __expf(xb) : 0.f;
                rsum += pa + pb; pk.d[1] = pk_bf16(pa, pb);
                xa = s1v + sB.x; xa = fmaxf(xa, 0.2f * xa);
                xb = s1v + sB.y; xb = fmaxf(xb, 0.2f * xb);
                pa = (bits & 16u) ? __expf(xa) : 0.f;
                pb = (bits & 32u) ? __expf(xb) : 0.f;
                rsum += pa + pb; pk.d[2] = pk_bf16(pa, pb);
                xa = s1v + sB.z; xa = fmaxf(xa, 0.2f * xa);
                xb = s1v + sB.w; xb = fmaxf(xb, 0.2f * xb);
                pa = (bits & 64u) ? __expf(xa) : 0.f;
                pb = (bits & 128u) ? __expf(xb) : 0.f;
                rsum += pa + pb; pk.d[3] = pk_bf16(pa, pb);
            }
            int kb = kc * 16 + st;
            const unsigned short* hs = hpb + (((size_t)kb * 4) << 9) + lane * 8;
            #pragma unroll
            for (int nf = 0; nf < 4; ++nf) {
                short8 Bf = *(const short8*)&hs[nf << 9];   // coalesced 1KB/wave
                acc[nf] = __builtin_amdgcn_mfma_f32_16x16x32_bf16(pk.s8, Bf, acc[nf], 0, 0, 0);
            }
        }
    }
    rsum += __shfl_xor(rsum, 16);
    rsum += __shfl_xor(rsum, 32);
    if (lane < 16) ps[kc][r] = rsum;
    if (kc > 0) {
        #pragma unroll
        for (int nf = 0; nf < 4; ++nf)
            #pragma unroll
            for (int q = 0; q < 4; ++q)
                red[kc - 1][4 * g + q][nf * 16 + r] = acc[nf][q];
    }
    __syncthreads();
    if (t < 16)
        rvl[t] = 1.0f / (ps[0][t] + ps[1][t] + ps[2][t] + ps[3][t]);
    __syncthreads();
    if (kc == 0) {
        #pragma unroll
        for (int nf = 0; nf < 4; ++nf) {
            #pragma unroll
            for (int q = 0; q < 4; ++q) {
                int m = 4 * g + q;               // C/D: row=(lane>>4)*4+reg
                int o = nf * 16 + r;             // C/D: col=lane&15
                float vv = acc[nf][q] + red[0][m][o] + red[1][m][o] + red[2][m][o];
                vv *= rvl[m];
                out[((size_t)b * N + m0 + m) * FOUT + o] = vv > 0.f ? vv : 0.f;
            }
        }
    }
}

extern "C" void kernel_launch(void* const* d_in, const int* in_sizes, int n_in,
                              void* d_out, int out_size, void* d_ws, size_t ws_size,
                              hipStream_t stream) {
    const float* inp = (const float*)d_in[0];   // (8,2048,128) f32
    const int*   adj = (const int*)d_in[1];     // (2048,2048) i32
    const float* W   = (const float*)d_in[2];   // (128,64) f32
    const float* a   = (const float*)d_in[3];   // (128,1) f32

    float* out = (float*)d_out;                        // (8,2048,64)
    float* att = out + (size_t)B * N * FOUT;           // (8,2048,2048)

    unsigned short* hP = (unsigned short*)d_ws;        // 2 MB bf16, packed
    float* s1  = (float*)(hP + (size_t)B * FOUT * N);  // 64 KB
    float* s2  = s1 + (size_t)B * N;                   // 64 KB
    unsigned long long* adjbits = (unsigned long long*)(s2 + (size_t)B * N); // 512 KB

    kA<<<384, 512, 0, stream>>>(inp, W, a, adj, hP, s1, s2, adjbits);
    k2<<<5120, 256, 0, stream>>>(s1, s2, adjbits, hP, att, out);
}

// Round 20
// 53.103 us; speedup vs baseline: 1.3930x; 1.3930x over previous
//
#include <hip/hip_runtime.h>
#include <hip/hip_bf16.h>

constexpr int B = 8, N = 2048, FIN = 128, FOUT = 64;

typedef __attribute__((ext_vector_type(8))) short short8;
typedef __attribute__((ext_vector_type(4))) float f32x4;

// f32 pair -> packed bf16 (RNE) via v_cvt_pk_bf16_f32
__device__ __forceinline__ unsigned int pk_bf16(float lo, float hi) {
    union { __hip_bfloat162 h2; unsigned int u; } c;
    c.h2 = __float22bfloat162_rn(float2{lo, hi});
    return c.u;
}
__device__ __forceinline__ unsigned short f2bf(float f) {
    return (unsigned short)(pk_bf16(f, 0.f) & 0xFFFFu);
}

// ---- kA: [blocks 0..127] h = inp@W via bf16 MFMA -> hP; s1/s2 in f32
//      [blocks 128..383] adj -> 1-bit mask   (unchanged from R18)
__global__ __launch_bounds__(512, 2) void kA(
        const float* __restrict__ inp, const float* __restrict__ W,
        const float* __restrict__ a, const int* __restrict__ adj,
        unsigned short* __restrict__ hP, float* __restrict__ s1,
        float* __restrict__ s2, unsigned long long* __restrict__ adjbits) {
    __shared__ float wa1l[128], wa2l[128];
    __shared__ unsigned short wT[64][136];
    __shared__ unsigned short aT[128][136];

    int bx = blockIdx.x, t = threadIdx.x, w = t >> 6, lane = t & 63;

    if (bx >= 128) {                              // ---- adj bit-pack ----
        int row = (bx - 128) * 8 + w;
        const int* ar = adj + (size_t)row * N;
        unsigned long long* br = adjbits + (size_t)row * 32;
        #pragma unroll 8
        for (int wq = 0; wq < 32; ++wq) {
            unsigned long long m = __ballot(ar[wq * 64 + lane] > 0);
            if (lane == 0) br[wq] = m;
        }
        return;
    }

    int b = bx >> 4, i0 = (bx & 15) * 128;

    if (t < 128) {
        const float* wr = W + t * FOUT;
        float acc1 = 0.f;
        #pragma unroll 16
        for (int o = 0; o < 64; ++o) acc1 = fmaf(wr[o], a[o], acc1);
        wa1l[t] = acc1;
    } else if (t < 256) {
        int k = t - 128;
        const float* wr = W + k * FOUT;
        float acc2 = 0.f;
        #pragma unroll 16
        for (int o = 0; o < 64; ++o) acc2 = fmaf(wr[o], a[64 + o], acc2);
        wa2l[k] = acc2;
    } else {
        int t2 = t - 256;
        int o = t2 & 63, kg = t2 >> 6;
        #pragma unroll 8
        for (int kk = 0; kk < 32; ++kk) {
            int k = kg * 32 + kk;
            wT[o][k] = f2bf(W[k * FOUT + o]);
        }
    }
    __syncthreads();

    {
        int row = t >> 2, seg = t & 3;
        const float* ip = inp + ((size_t)b * N + i0 + row) * FIN + seg * 32;
        float s1p = 0.f, s2p = 0.f;
        #pragma unroll
        for (int q = 0; q < 8; ++q) {
            float4 v = *(const float4*)&ip[q * 4];
            int k = seg * 32 + q * 4;
            s1p += v.x * wa1l[k] + v.y * wa1l[k + 1] + v.z * wa1l[k + 2] + v.w * wa1l[k + 3];
            s2p += v.x * wa2l[k] + v.y * wa2l[k + 1] + v.z * wa2l[k + 2] + v.w * wa2l[k + 3];
            unsigned int* dst = (unsigned int*)&aT[row][k];
            dst[0] = pk_bf16(v.x, v.y);
            dst[1] = pk_bf16(v.z, v.w);
        }
        s1p += __shfl_xor(s1p, 1); s1p += __shfl_xor(s1p, 2);
        s2p += __shfl_xor(s2p, 1); s2p += __shfl_xor(s2p, 2);
        if (seg == 0) {
            s1[(size_t)b * N + i0 + row] = s1p;
            s2[(size_t)b * N + i0 + row] = s2p;
        }
    }
    __syncthreads();

    int r = lane & 15, g = lane >> 4;
    int mloc = w * 16;
    f32x4 acc[4];
    #pragma unroll
    for (int nf = 0; nf < 4; ++nf)
        #pragma unroll
        for (int q = 0; q < 4; ++q) acc[nf][q] = 0.f;
    #pragma unroll
    for (int ks = 0; ks < 4; ++ks) {
        short8 Af = *(const short8*)&aT[mloc + r][ks * 32 + g * 8];
        #pragma unroll
        for (int nf = 0; nf < 4; ++nf) {
            short8 Bf = *(const short8*)&wT[nf * 16 + r][ks * 32 + g * 8];
            acc[nf] = __builtin_amdgcn_mfma_f32_16x16x32_bf16(Af, Bf, acc[nf], 0, 0, 0);
        }
    }
    __syncthreads();

    #pragma unroll
    for (int nf = 0; nf < 4; ++nf)
        #pragma unroll
        for (int q = 0; q < 4; ++q)
            aT[mloc + g * 4 + q][nf * 16 + r] = f2bf(acc[nf][q]);
    __syncthreads();

    #pragma unroll
    for (int half = 0; half < 2; ++half) {
        int idx = t + half * 512;
        int kb_l = idx >> 8, nf = (idx >> 6) & 3, ln = idx & 63;
        int g2 = ln >> 4, r2 = ln & 15;
        union { short8 s8; unsigned short u[8]; } tw;
        #pragma unroll
        for (int e = 0; e < 8; ++e)
            tw.u[e] = aT[kb_l * 32 + g2 * 8 + e][nf * 16 + r2];
        int kbg = (bx & 15) * 4 + kb_l;
        *(short8*)&hP[((((size_t)b * 64 + kbg) * 4 + nf) << 9) + ln * 8] = tw.s8;
    }
}

// ---- K2 fused (same-block sequential): pass A = R18's proven PV body;
//      then out-write (frees acc); then pass B = this block's 16 att rows.
// Removes the k2a->k2b inter-kernel barrier: each block streams its att
// rows as soon as ITS PV is done. 256 thr / 4 waves; 16 rows/block;
// grid 1024 (b = L&7). No rvg round-trip.
__global__ __launch_bounds__(256, 2) void k2_fused(
        const float* __restrict__ s1g, const float* __restrict__ s2g,
        const unsigned long long* __restrict__ adjbits,
        const unsigned short* __restrict__ hP,
        float* __restrict__ att, float* __restrict__ out) {
    __shared__ float s2l[N];                 // 8 KB
    __shared__ float s1l[16];
    __shared__ float ps[4][16];
    __shared__ float rvl[16];
    __shared__ float red[3][16][68];         // 13 KB

    int L = blockIdx.x;
    int b = L & 7, m0 = (L >> 3) * 16;
    int t = threadIdx.x, kc = t >> 6, lane = t & 63;
    int r = lane & 15, g = lane >> 4;

    {
        int j = t * 8;
        *(float4*)&s2l[j]     = *(const float4*)&s2g[(size_t)b * N + j];
        *(float4*)&s2l[j + 4] = *(const float4*)&s2g[(size_t)b * N + j + 4];
    }
    if (t < 16) s1l[t] = s1g[(size_t)b * N + m0 + t];
    __syncthreads();

    float s1v = s1l[r];
    const unsigned long long* brow = adjbits + (size_t)(m0 + r) * 32 + kc * 8;
    const unsigned short* hpb = hP + (size_t)b * 64 * 4 * 512;

    f32x4 acc[4];
    #pragma unroll
    for (int nf = 0; nf < 4; ++nf)
        #pragma unroll
        for (int q = 0; q < 4; ++q) acc[nf][q] = 0.f;
    float rsum = 0.f;

    // ---- pass A: PV MFMA, rolled-window body (R18, proven no-spill) -------
    #pragma unroll 1
    for (int so = 0; so < 4; ++so) {             // rolled: bounds load window
        unsigned long long bw0 = brow[so * 2];
        unsigned long long bw1 = brow[so * 2 + 1];
        #pragma unroll
        for (int si = 0; si < 4; ++si) {         // full unroll: 4-step window
            int st = so * 4 + si;
            int jb = kc * 512 + st * 32 + g * 8;
            unsigned long long bwv = (si < 2) ? bw0 : bw1;
            unsigned int bits = (unsigned int)(bwv >> ((si & 1) * 32 + g * 8)) & 0xFFu;
            float4 sA = *(const float4*)&s2l[jb];
            float4 sB = *(const float4*)&s2l[jb + 4];
            union { short8 s8; unsigned int d[4]; } pk;
            {   // pairwise: <=4 live f32 temporaries at a time
                float xa, xb, pa, pb;
                xa = s1v + sA.x; xa = fmaxf(xa, 0.2f * xa);
                xb = s1v + sA.y; xb = fmaxf(xb, 0.2f * xb);
                pa = (bits & 1u) ? __expf(xa) : 0.f;
                pb = (bits & 2u) ? __expf(xb) : 0.f;
                rsum += pa + pb; pk.d[0] = pk_bf16(pa, pb);
                xa = s1v + sA.z; xa = fmaxf(xa, 0.2f * xa);
                xb = s1v + sA.w; xb = fmaxf(xb, 0.2f * xb);
                pa = (bits & 4u) ? __expf(xa) : 0.f;
                pb = (bits & 8u) ? __expf(xb) : 0.f;
                rsum += pa + pb; pk.d[1] = pk_bf16(pa, pb);
                xa = s1v + sB.x; xa = fmaxf(xa, 0.2f * xa);
                xb = s1v + sB.y; xb = fmaxf(xb, 0.2f * xb);
                pa = (bits & 16u) ? __expf(xa) : 0.f;
                pb = (bits & 32u) ? __expf(xb) : 0.f;
                rsum += pa + pb; pk.d[2] = pk_bf16(pa, pb);
                xa = s1v + sB.z; xa = fmaxf(xa, 0.2f * xa);
                xb = s1v + sB.w; xb = fmaxf(xb, 0.2f * xb);
                pa = (bits & 64u) ? __expf(xa) : 0.f;
                pb = (bits & 128u) ? __expf(xb) : 0.f;
                rsum += pa + pb; pk.d[3] = pk_bf16(pa, pb);
            }
            int kb = kc * 16 + st;
            const unsigned short* hs = hpb + (((size_t)kb * 4) << 9) + lane * 8;
            #pragma unroll
            for (int nf = 0; nf < 4; ++nf) {
                short8 Bf = *(const short8*)&hs[nf << 9];   // coalesced 1KB/wave
                acc[nf] = __builtin_amdgcn_mfma_f32_16x16x32_bf16(pk.s8, Bf, acc[nf], 0, 0, 0);
            }
        }
    }
    rsum += __shfl_xor(rsum, 16);
    rsum += __shfl_xor(rsum, 32);
    if (lane < 16) ps[kc][r] = rsum;
    if (kc > 0) {
        #pragma unroll
        for (int nf = 0; nf < 4; ++nf)
            #pragma unroll
            for (int q = 0; q < 4; ++q)
                red[kc - 1][4 * g + q][nf * 16 + r] = acc[nf][q];
    }
    __syncthreads();
    if (t < 16)
        rvl[t] = 1.0f / (ps[0][t] + ps[1][t] + ps[2][t] + ps[3][t]);
    __syncthreads();

    // ---- out-write (kc==0): frees acc before the streaming phase ----------
    if (kc == 0) {
        #pragma unroll
        for (int nf = 0; nf < 4; ++nf) {
            #pragma unroll
            for (int q = 0; q < 4; ++q) {
                int m = 4 * g + q;               // C/D: row=(lane>>4)*4+reg
                int o = nf * 16 + r;             // C/D: col=lane&15
                float vv = acc[nf][q] + red[0][m][o] + red[1][m][o] + red[2][m][o];
                vv *= rvl[m];
                out[((size_t)b * N + m0 + m) * FOUT + o] = vv > 0.f ? vv : 0.f;
            }
        }
    }

    // ---- pass B: stream this block's 16 att rows (wave w -> rows 4w..4w+3)
    #pragma unroll
    for (int rr = 0; rr < 4; ++rr) {
        int row = kc * 4 + rr;
        float s1r = s1l[row];
        float rvr = rvl[row];
        const unsigned long long* br2 = adjbits + (size_t)(m0 + row) * 32;
        float* orow = att + ((size_t)b * N + m0 + row) * N;
        #pragma unroll
        for (int it = 0; it < 8; ++it) {
            int j = it * 256 + lane * 4;
            unsigned int bits = (unsigned int)(br2[j >> 6] >> (j & 63)) & 0xFu;
            float4 sv = *(const float4*)&s2l[j];
            float x0 = s1r + sv.x; x0 = fmaxf(x0, 0.2f * x0);
            float x1 = s1r + sv.y; x1 = fmaxf(x1, 0.2f * x1);
            float x2 = s1r + sv.z; x2 = fmaxf(x2, 0.2f * x2);
            float x3 = s1r + sv.w; x3 = fmaxf(x3, 0.2f * x3);
            float4 o;
            o.x = (bits & 1u) ? __expf(x0) * rvr : 0.f;
            o.y = (bits & 2u) ? __expf(x1) * rvr : 0.f;
            o.z = (bits & 4u) ? __expf(x2) * rvr : 0.f;
            o.w = (bits & 8u) ? __expf(x3) * rvr : 0.f;
            *(float4*)&orow[j] = o;              // 1KB/wave contiguous
        }
    }
}

extern "C" void kernel_launch(void* const* d_in, const int* in_sizes, int n_in,
                              void* d_out, int out_size, void* d_ws, size_t ws_size,
                              hipStream_t stream) {
    const float* inp = (const float*)d_in[0];   // (8,2048,128) f32
    const int*   adj = (const int*)d_in[1];     // (2048,2048) i32
    const float* W   = (const float*)d_in[2];   // (128,64) f32
    const float* a   = (const float*)d_in[3];   // (128,1) f32

    float* out = (float*)d_out;                        // (8,2048,64)
    float* att = out + (size_t)B * N * FOUT;           // (8,2048,2048)

    unsigned short* hP = (unsigned short*)d_ws;        // 2 MB bf16, packed
    float* s1  = (float*)(hP + (size_t)B * FOUT * N);  // 64 KB
    float* s2  = s1 + (size_t)B * N;                   // 64 KB
    unsigned long long* adjbits = (unsigned long long*)(s2 + (size_t)B * N); // 512 KB

    kA<<<384, 512, 0, stream>>>(inp, W, a, adj, hP, s1, s2, adjbits);
    k2_fused<<<1024, 256, 0, stream>>>(s1, s2, adjbits, hP, att, out);
}